// Round 11
// baseline (331.407 us; speedup 1.0000x reference)
//
#include <hip/hip_runtime.h>
#include <hip/hip_bf16.h>

#define EMB 512
#define NSTK 32
#define NPNT 64
#define BSZ 32

// Weight-panel LDS geometry: 4 k-chunk planes, padded stride -> conflict-free
#define WPLANE 8208              // bytes: 512 o * 16B + 16B pad  (513*16)
#define WPANEL (4 * WPLANE)      // one 32-k panel
typedef __attribute__((ext_vector_type(8))) _Float16 f16x8;
typedef __attribute__((ext_vector_type(4))) float f32x4;
typedef __attribute__((ext_vector_type(4))) unsigned short us4;
typedef __attribute__((ext_vector_type(8))) unsigned short us8;

static __device__ __forceinline__ unsigned short f16bits(float x) {
    _Float16 h = (_Float16)x;
    return *reinterpret_cast<unsigned short*>(&h);
}

// async global->LDS DMA: dest = wave-uniform lds base + lane*16 (m104 semantics)
#define GLL(gsrc, ldst)                                                         \
    __builtin_amdgcn_global_load_lds(                                           \
        (const __attribute__((address_space(1))) void*)(gsrc),                  \
        (__attribute__((address_space(3))) void*)(ldst), 16, 0, 0)

// ---------------------------------------------------------------------------
// Kernel A: convert Wk and Wg (fp32 512x512) to f16.
// ---------------------------------------------------------------------------
__global__ void cvt_weights(const float* __restrict__ wk,
                            const float* __restrict__ wg,
                            _Float16* __restrict__ wkf,
                            _Float16* __restrict__ wgf) {
    int idx = blockIdx.x * blockDim.x + threadIdx.x;   // 0..131071, 4 elems each
    const float* src;
    _Float16* dst;
    int k;
    if (idx < 65536) { src = wk; dst = wkf; k = idx; }
    else             { src = wg; dst = wgf; k = idx - 65536; }
    f32x4 v = *reinterpret_cast<const f32x4*>(src + (size_t)k * 4);
    us4 o;
#pragma unroll
    for (int e = 0; e < 4; ++e) o[e] = f16bits(v[e]);
    *reinterpret_cast<us4*>(dst + (size_t)k * 4) = o;
}

// ---------------------------------------------------------------------------
// Kernel B: sp_q / sp_v — fp32 GEMM (unchanged).
// ---------------------------------------------------------------------------
__global__ __launch_bounds__(256)
void qv_gemm(const float* __restrict__ sparse,
             const float* __restrict__ Wq, const float* __restrict__ sq, const float* __restrict__ bq,
             const float* __restrict__ Wv, const float* __restrict__ sv, const float* __restrict__ bv,
             float* __restrict__ outq, float* __restrict__ outv) {
    const float* W  = (blockIdx.z == 0) ? Wq : Wv;
    const float* sc = (blockIdx.z == 0) ? sq : sv;
    const float* bi = (blockIdx.z == 0) ? bq : bv;
    float* orow     = (blockIdx.z == 0) ? outq : outv;

    __shared__ float Wt[64][33];
    __shared__ float St[32][65];

    const int m0 = blockIdx.x * 64;
    const int o0 = blockIdx.y * 64;
    const int t  = threadIdx.x;
    const int ty = t >> 4, tx = t & 15;

    float acc[4][4] = {};

    for (int k0 = 0; k0 < 512; k0 += 32) {
        {
            int ol = t >> 2, kl = (t & 3) * 8;
            const float* p = W + (size_t)(o0 + ol) * 512 + k0 + kl;
            f32x4 v0 = *reinterpret_cast<const f32x4*>(p);
            f32x4 v1 = *reinterpret_cast<const f32x4*>(p + 4);
#pragma unroll
            for (int e = 0; e < 4; ++e) { Wt[ol][kl + e] = v0[e]; Wt[ol][kl + 4 + e] = v1[e]; }
        }
        {
            int kl = t >> 3, ml = (t & 7) * 8;
            int mm = m0 + ml;
            int bb = mm >> 5, iidx = mm & 31;
            const float* p = sparse + (size_t)bb * 16384 + (size_t)(k0 + kl) * 32 + iidx;
            f32x4 v0 = *reinterpret_cast<const f32x4*>(p);
            f32x4 v1 = *reinterpret_cast<const f32x4*>(p + 4);
#pragma unroll
            for (int e = 0; e < 4; ++e) { St[kl][ml + e] = v0[e]; St[kl][ml + 4 + e] = v1[e]; }
        }
        __syncthreads();
#pragma unroll
        for (int kk = 0; kk < 32; ++kk) {
            float av[4], bvv[4];
#pragma unroll
            for (int e = 0; e < 4; ++e) av[e]  = Wt[ty * 4 + e][kk];
#pragma unroll
            for (int e = 0; e < 4; ++e) bvv[e] = St[kk][tx * 4 + e];
#pragma unroll
            for (int a = 0; a < 4; ++a)
#pragma unroll
                for (int bb2 = 0; bb2 < 4; ++bb2) acc[a][bb2] += av[a] * bvv[bb2];
        }
        __syncthreads();
    }
#pragma unroll
    for (int ae = 0; ae < 4; ++ae) {
        int o = o0 + ty * 4 + ae;
        float s = sc[o], bb2 = bi[o];
#pragma unroll
        for (int be = 0; be < 4; ++be) {
            int mm = m0 + tx * 4 + be;
            float h = acc[ae][be] * s + bb2;
            h = (h >= 0.f) ? h : 0.2f * h;
            orow[(size_t)mm * 512 + o] = h;
        }
    }
}

// ---------------------------------------------------------------------------
// Kernel C: fused main. One WG (16 waves, 1024 thr) per (b,i).
// f16 MFMA GEMMs; weight K-panels DMA'd via global_load_lds into a
// conflict-free 4-plane layout (plane stride 8208B):
//   chunk (o, t) at  t*WPLANE + o*16   ->  af granule start = 16*((l15+lk)%8)
// XH keeps the 520-elem row pad (also conflict-free).
// ---------------------------------------------------------------------------
__global__ __launch_bounds__(1024, 4)
void fused_attn(const float* __restrict__ dense,
                const _Float16* __restrict__ wkf,
                const _Float16* __restrict__ wgf,
                const float* __restrict__ wsq,
                const float* __restrict__ wsv,
                const float* __restrict__ sk, const float* __restrict__ bk,
                const float* __restrict__ sg, const float* __restrict__ bg,
                float* __restrict__ out) {
    __shared__ __align__(16) _Float16 XH[64][520];        // 66.5 KB, X -> D (f16)
    __shared__ __align__(16) char WPbuf[2][WPANEL];       // 2 x 32.8 KB panels
    __shared__ __align__(16) float qrow[512];
    __shared__ __align__(16) float vrow[512];
    __shared__ float wredA[16][64];
    __shared__ float wredB[16][64];

    const int m   = blockIdx.x;        // 0..1023
    const int b   = m >> 5, ii = m & 31;
    const int tid = threadIdx.x;       // 0..1023
    const int w   = tid >> 6;          // wave 0..15
    const int l   = tid & 63;
    const int l15 = l & 15;
    const int lk  = l >> 4;            // 0..3

    // window ids for this wave's 2 GLLs: id = w*2+ih -> plane t=id>>3, oblk=id&7
    const int id0 = w * 2, id1 = w * 2 + 1;
    const int t0 = id0 >> 3, ob0 = id0 & 7;
    const int t1 = id1 >> 3, ob1 = id1 & 7;

    // ---- prologue: DMA Wk panel 0 into WPbuf[0] (overlaps X staging)
    {
        GLL(wkf + (size_t)(ob0 * 64 + l) * 512 + t0 * 8,
            WPbuf[0] + t0 * WPLANE + ob0 * 1024);
        GLL(wkf + (size_t)(ob1 * 64 + l) * 512 + t1 * 8,
            WPbuf[0] + t1 * WPLANE + ob1 * 1024);
    }

    if (tid < 512) qrow[tid] = wsq[(size_t)m * 512 + tid];
    else           vrow[tid - 512] = wsv[(size_t)m * 512 + (tid - 512)];

    {   // stage X (f16): thread owns j-row l, c-block [w*32, +32)
        const float* src = dense + (size_t)b * 512 * 2048 + (size_t)ii * 64 + l;
#pragma unroll
        for (int e8 = 0; e8 < 4; ++e8) {
            const int c0 = w * 32 + e8 * 8;
            us8 pk;
#pragma unroll
            for (int e = 0; e < 8; ++e)
                pk[e] = f16bits(src[(size_t)(c0 + e) * 2048]);
            *reinterpret_cast<us8*>(&XH[l][c0]) = pk;
        }
    }
    __syncthreads();   // drains the panel-0 DMA too

    f32x4 acc[2][4];
#pragma unroll
    for (int fm = 0; fm < 2; ++fm)
#pragma unroll
        for (int fn = 0; fn < 4; ++fn) acc[fm][fn] = (f32x4){0.f, 0.f, 0.f, 0.f};

    // ---- GEMM1: dn_k[o,j] = sum_c Wk[o,c] * X[c,j]
    for (int ks = 0; ks < 16; ++ks) {
        {   // prefetch next panel (last iter prefetches Wg panel 0)
            const _Float16* wsp = (ks < 15) ? (wkf + (size_t)(ks + 1) * 32) : wgf;
            char* pb = WPbuf[(ks + 1) & 1];
            GLL(wsp + (size_t)(ob0 * 64 + l) * 512 + t0 * 8, pb + t0 * WPLANE + ob0 * 1024);
            GLL(wsp + (size_t)(ob1 * 64 + l) * 512 + t1 * 8, pb + t1 * WPLANE + ob1 * 1024);
        }
        {   // compute from WPbuf[ks&1]
            const char* pbuf = WPbuf[ks & 1];
            f16x8 af[2], bf[4];
#pragma unroll
            for (int fm = 0; fm < 2; ++fm)
                af[fm] = *reinterpret_cast<const f16x8*>(
                    pbuf + lk * WPLANE + (w * 32 + fm * 16 + l15) * 16);
#pragma unroll
            for (int fn = 0; fn < 4; ++fn)
                bf[fn] = *reinterpret_cast<const f16x8*>(&XH[fn * 16 + l15][ks * 32 + lk * 8]);
#pragma unroll
            for (int fm = 0; fm < 2; ++fm)
#pragma unroll
                for (int fn = 0; fn < 4; ++fn)
                    acc[fm][fn] = __builtin_amdgcn_mfma_f32_16x16x32_f16(af[fm], bf[fn], acc[fm][fn], 0, 0, 0);
        }
        __syncthreads();   // next panel ready, buffers safe
    }

    // ---- epilogue1: d = q - lrelu(acc*sk+bk), f16, write D over XH
#pragma unroll
    for (int fm = 0; fm < 2; ++fm) {
        const int o0 = w * 32 + fm * 16 + lk * 4;
        f32x4 skv = *reinterpret_cast<const f32x4*>(sk + o0);
        f32x4 bkv = *reinterpret_cast<const f32x4*>(bk + o0);
        f32x4 qv4 = *reinterpret_cast<const f32x4*>(&qrow[o0]);
#pragma unroll
        for (int fn = 0; fn < 4; ++fn) {
            const int j = fn * 16 + l15;
            us4 pkh;
#pragma unroll
            for (int r = 0; r < 4; ++r) {
                float h = acc[fm][fn][r] * skv[r] + bkv[r];
                h = (h >= 0.f) ? h : 0.2f * h;
                pkh[r] = f16bits(qv4[r] - h);
            }
            *reinterpret_cast<us4*>(&XH[j][o0]) = pkh;   // 8B store, o0 % 4 == 0
        }
    }
    __syncthreads();

    // ---- GEMM2: g[oo,j] = sum_o Wg[oo,o] * d[o,j]
#pragma unroll
    for (int fm = 0; fm < 2; ++fm)
#pragma unroll
        for (int fn = 0; fn < 4; ++fn) acc[fm][fn] = (f32x4){0.f, 0.f, 0.f, 0.f};

    for (int ks = 0; ks < 16; ++ks) {
        if (ks < 15) {   // prefetch next Wg panel
            const _Float16* wsp = wgf + (size_t)(ks + 1) * 32;
            char* pb = WPbuf[(ks + 1) & 1];
            GLL(wsp + (size_t)(ob0 * 64 + l) * 512 + t0 * 8, pb + t0 * WPLANE + ob0 * 1024);
            GLL(wsp + (size_t)(ob1 * 64 + l) * 512 + t1 * 8, pb + t1 * WPLANE + ob1 * 1024);
        }
        {
            const char* pbuf = WPbuf[ks & 1];
            f16x8 af[2], bf[4];
#pragma unroll
            for (int fm = 0; fm < 2; ++fm)
                af[fm] = *reinterpret_cast<const f16x8*>(
                    pbuf + lk * WPLANE + (w * 32 + fm * 16 + l15) * 16);
#pragma unroll
            for (int fn = 0; fn < 4; ++fn)
                bf[fn] = *reinterpret_cast<const f16x8*>(&XH[fn * 16 + l15][ks * 32 + lk * 8]);
#pragma unroll
            for (int fm = 0; fm < 2; ++fm)
#pragma unroll
                for (int fn = 0; fn < 4; ++fn)
                    acc[fm][fn] = __builtin_amdgcn_mfma_f32_16x16x32_f16(af[fm], bf[fn], acc[fm][fn], 0, 0, 0);
        }
        __syncthreads();
    }

    // ---- epilogue2 in place: g = lrelu(acc*sg+bg)
#pragma unroll
    for (int fm = 0; fm < 2; ++fm) {
        const int o0 = w * 32 + fm * 16 + lk * 4;
        f32x4 sgv = *reinterpret_cast<const f32x4*>(sg + o0);
        f32x4 bgv = *reinterpret_cast<const f32x4*>(bg + o0);
#pragma unroll
        for (int fn = 0; fn < 4; ++fn)
#pragma unroll
            for (int r = 0; r < 4; ++r) {
                float h = acc[fm][fn][r] * sgv[r] + bgv[r];
                acc[fm][fn][r] = (h >= 0.f) ? h : 0.2f * h;
            }
    }

    // ---- softmax over the 512 channels, per j column
    float pm[4];
#pragma unroll
    for (int fn = 0; fn < 4; ++fn) {
        float mx = -1e30f;
#pragma unroll
        for (int fm = 0; fm < 2; ++fm)
#pragma unroll
            for (int r = 0; r < 4; ++r) mx = fmaxf(mx, acc[fm][fn][r]);
        mx = fmaxf(mx, __shfl_xor(mx, 16, 64));
        mx = fmaxf(mx, __shfl_xor(mx, 32, 64));
        pm[fn] = mx;
    }
    if (l < 16) {
#pragma unroll
        for (int fn = 0; fn < 4; ++fn) wredA[w][fn * 16 + l] = pm[fn];
    }
    __syncthreads();

    float jmax[4];
#pragma unroll
    for (int fn = 0; fn < 4; ++fn) {
        float mx = wredA[0][fn * 16 + l15];
#pragma unroll
        for (int ww = 1; ww < 16; ++ww) mx = fmaxf(mx, wredA[ww][fn * 16 + l15]);
        jmax[fn] = mx;
    }

    float ps[4] = {0.f, 0.f, 0.f, 0.f};
#pragma unroll
    for (int fm = 0; fm < 2; ++fm)
#pragma unroll
        for (int fn = 0; fn < 4; ++fn)
#pragma unroll
            for (int r = 0; r < 4; ++r) {
                float e = __expf(acc[fm][fn][r] - jmax[fn]);
                acc[fm][fn][r] = e;
                ps[fn] += e;
            }
#pragma unroll
    for (int fn = 0; fn < 4; ++fn) {
        ps[fn] += __shfl_xor(ps[fn], 16, 64);
        ps[fn] += __shfl_xor(ps[fn], 32, 64);
    }
    if (l < 16) {
#pragma unroll
        for (int fn = 0; fn < 4; ++fn) wredB[w][fn * 16 + l] = ps[fn];
    }
    __syncthreads();

    float rinv[4];
#pragma unroll
    for (int fn = 0; fn < 4; ++fn) {
        float s = 0.f;
#pragma unroll
        for (int ww = 0; ww < 16; ++ww) s += wredB[ww][fn * 16 + l15];
        rinv[fn] = 1.f / s;
    }

    // ---- out[b,oo,i] = sp_v[oo] * sum_j coef[oo,j]   (FP32 store)
#pragma unroll
    for (int fm = 0; fm < 2; ++fm) {
#pragma unroll
        for (int r = 0; r < 4; ++r) {
            float tsum = 0.f;
#pragma unroll
            for (int fn = 0; fn < 4; ++fn) tsum += acc[fm][fn][r] * rinv[fn];
            tsum += __shfl_xor(tsum, 1, 64);
            tsum += __shfl_xor(tsum, 2, 64);
            tsum += __shfl_xor(tsum, 4, 64);
            tsum += __shfl_xor(tsum, 8, 64);
            if (l15 == 0) {
                int oo = w * 32 + fm * 16 + lk * 4 + r;
                out[((size_t)b * 512 + oo) * 32 + ii] = vrow[oo] * tsum;
            }
        }
    }
}

// ---------------------------------------------------------------------------
extern "C" void kernel_launch(void* const* d_in, const int* in_sizes, int n_in,
                              void* d_out, int out_size, void* d_ws, size_t ws_size,
                              hipStream_t stream) {
    const float* sparse = (const float*)d_in[0];
    const float* dense  = (const float*)d_in[1];
    const float* Wq = (const float*)d_in[2];
    const float* sq = (const float*)d_in[3];
    const float* bq = (const float*)d_in[4];
    const float* Wk = (const float*)d_in[5];
    const float* sk = (const float*)d_in[6];
    const float* bk = (const float*)d_in[7];
    const float* Wv = (const float*)d_in[8];
    const float* sv = (const float*)d_in[9];
    const float* bv = (const float*)d_in[10];
    const float* Wg = (const float*)d_in[11];
    const float* sg = (const float*)d_in[12];
    const float* bg = (const float*)d_in[13];
    float* out = (float*)d_out;

    // workspace: [sp_q f32 2MB][sp_v f32 2MB][Wk f16 512KB][Wg f16 512KB]
    float* wsq = (float*)d_ws;
    float* wsv = wsq + 1024 * 512;
    _Float16* wkf = (_Float16*)(wsv + 1024 * 512);
    _Float16* wgf = wkf + 512 * 512;

    cvt_weights<<<512, 256, 0, stream>>>(Wk, Wg, wkf, wgf);
    qv_gemm<<<dim3(16, 8, 2), 256, 0, stream>>>(sparse, Wq, sq, bq, Wv, sv, bv, wsq, wsv);
    fused_attn<<<1024, 1024, 0, stream>>>(dense, wkf, wgf, wsq, wsv, sk, bk, sg, bg, out);
}

// Round 12
// 191.305 us; speedup vs baseline: 1.7323x; 1.7323x over previous
//
#include <hip/hip_runtime.h>
#include <hip/hip_bf16.h>

#define EMB 512
#define NSTK 32
#define NPNT 64
#define BSZ 32

typedef __attribute__((ext_vector_type(8))) _Float16 f16x8;
typedef __attribute__((ext_vector_type(4))) float f32x4;
typedef __attribute__((ext_vector_type(4))) unsigned short us4;
typedef __attribute__((ext_vector_type(8))) unsigned short us8;

static __device__ __forceinline__ unsigned short f16bits(float x) {
    _Float16 h = (_Float16)x;
    return *reinterpret_cast<unsigned short*>(&h);
}

// async global->LDS DMA: dest = wave-uniform lds base + lane*16 (m104 semantics)
#define GLL(gsrc, ldst)                                                         \
    __builtin_amdgcn_global_load_lds(                                           \
        (const __attribute__((address_space(1))) void*)(gsrc),                  \
        (__attribute__((address_space(3))) void*)(ldst), 16, 0, 0)

// ---------------------------------------------------------------------------
// Kernel A: convert Wk and Wg (fp32 512x512) to f16.
// ---------------------------------------------------------------------------
__global__ void cvt_weights(const float* __restrict__ wk,
                            const float* __restrict__ wg,
                            _Float16* __restrict__ wkf,
                            _Float16* __restrict__ wgf) {
    int idx = blockIdx.x * blockDim.x + threadIdx.x;   // 0..131071, 4 elems each
    const float* src;
    _Float16* dst;
    int k;
    if (idx < 65536) { src = wk; dst = wkf; k = idx; }
    else             { src = wg; dst = wgf; k = idx - 65536; }
    f32x4 v = *reinterpret_cast<const f32x4*>(src + (size_t)k * 4);
    us4 o;
#pragma unroll
    for (int e = 0; e < 4; ++e) o[e] = f16bits(v[e]);
    *reinterpret_cast<us4*>(dst + (size_t)k * 4) = o;
}

// ---------------------------------------------------------------------------
// Kernel B: sp_q / sp_v — fp32 GEMM (unchanged).
// ---------------------------------------------------------------------------
__global__ __launch_bounds__(256)
void qv_gemm(const float* __restrict__ sparse,
             const float* __restrict__ Wq, const float* __restrict__ sq, const float* __restrict__ bq,
             const float* __restrict__ Wv, const float* __restrict__ sv, const float* __restrict__ bv,
             float* __restrict__ outq, float* __restrict__ outv) {
    const float* W  = (blockIdx.z == 0) ? Wq : Wv;
    const float* sc = (blockIdx.z == 0) ? sq : sv;
    const float* bi = (blockIdx.z == 0) ? bq : bv;
    float* orow     = (blockIdx.z == 0) ? outq : outv;

    __shared__ float Wt[64][33];
    __shared__ float St[32][65];

    const int m0 = blockIdx.x * 64;
    const int o0 = blockIdx.y * 64;
    const int t  = threadIdx.x;
    const int ty = t >> 4, tx = t & 15;

    float acc[4][4] = {};

    for (int k0 = 0; k0 < 512; k0 += 32) {
        {
            int ol = t >> 2, kl = (t & 3) * 8;
            const float* p = W + (size_t)(o0 + ol) * 512 + k0 + kl;
            f32x4 v0 = *reinterpret_cast<const f32x4*>(p);
            f32x4 v1 = *reinterpret_cast<const f32x4*>(p + 4);
#pragma unroll
            for (int e = 0; e < 4; ++e) { Wt[ol][kl + e] = v0[e]; Wt[ol][kl + 4 + e] = v1[e]; }
        }
        {
            int kl = t >> 3, ml = (t & 7) * 8;
            int mm = m0 + ml;
            int bb = mm >> 5, iidx = mm & 31;
            const float* p = sparse + (size_t)bb * 16384 + (size_t)(k0 + kl) * 32 + iidx;
            f32x4 v0 = *reinterpret_cast<const f32x4*>(p);
            f32x4 v1 = *reinterpret_cast<const f32x4*>(p + 4);
#pragma unroll
            for (int e = 0; e < 4; ++e) { St[kl][ml + e] = v0[e]; St[kl][ml + 4 + e] = v1[e]; }
        }
        __syncthreads();
#pragma unroll
        for (int kk = 0; kk < 32; ++kk) {
            float av[4], bvv[4];
#pragma unroll
            for (int e = 0; e < 4; ++e) av[e]  = Wt[ty * 4 + e][kk];
#pragma unroll
            for (int e = 0; e < 4; ++e) bvv[e] = St[kk][tx * 4 + e];
#pragma unroll
            for (int a = 0; a < 4; ++a)
#pragma unroll
                for (int bb2 = 0; bb2 < 4; ++bb2) acc[a][bb2] += av[a] * bvv[bb2];
        }
        __syncthreads();
    }
#pragma unroll
    for (int ae = 0; ae < 4; ++ae) {
        int o = o0 + ty * 4 + ae;
        float s = sc[o], bb2 = bi[o];
#pragma unroll
        for (int be = 0; be < 4; ++be) {
            int mm = m0 + tx * 4 + be;
            float h = acc[ae][be] * s + bb2;
            h = (h >= 0.f) ? h : 0.2f * h;
            orow[(size_t)mm * 512 + o] = h;
        }
    }
}

// ---------------------------------------------------------------------------
// Kernel C: fused main. One WG (16 waves, 1024 thr) per (b,i).
// f16 MFMA GEMMs; weight K-panels double-buffered via global_load_lds with a
// PRE-SWIZZLED GLOBAL SOURCE (m173): LDS dest stays linear (lane*16), but each
// lane fetches k-chunk t = ((l&3) - ((l>>3)&3)) & 3 of its row, so chunk t of
// row o sits in slot (t + ((o&15)>>1)) & 3.  The af read then covers all 8
// 16B-granule bank-starts exactly twice (minimum 2-way) instead of 8-way.
// Global coalescing is identical to R10 (4-lane groups read one 64B segment).
// ---------------------------------------------------------------------------
__global__ __launch_bounds__(1024, 4)
void fused_attn(const float* __restrict__ dense,
                const _Float16* __restrict__ wkf,
                const _Float16* __restrict__ wgf,
                const float* __restrict__ wsq,
                const float* __restrict__ wsv,
                const float* __restrict__ sk, const float* __restrict__ bk,
                const float* __restrict__ sg, const float* __restrict__ bg,
                float* __restrict__ out) {
    __shared__ __align__(16) _Float16 XH[64][520];     // 66.5 KB, X -> D (f16)
    __shared__ __align__(16) _Float16 WP[2][512 * 32]; // 2 x 32 KB weight panels
    __shared__ __align__(16) float qrow[512];
    __shared__ __align__(16) float vrow[512];
    __shared__ float wredA[16][64];
    __shared__ float wredB[16][64];

    const int m   = blockIdx.x;        // 0..1023
    const int b   = m >> 5, ii = m & 31;
    const int tid = threadIdx.x;       // 0..1023
    const int w   = tid >> 6;          // wave 0..15
    const int l   = tid & 63;
    const int l15 = l & 15;
    const int lk  = l >> 4;            // 0..3

    // swizzled k-chunk this lane DMAs: slot s = l&3 holds chunk (s - h) & 3,
    // h = (o_rel>>1)&3 with o_rel = l>>2
    const int tsw = ((l & 3) - ((l >> 3) & 3)) & 3;
    const int orl = l >> 2;

    // ---- prologue: DMA Wk panel 0 into WP[0] (overlaps X staging)
    {
#pragma unroll
        for (int ih = 0; ih < 2; ++ih) {
            const int o = w * 32 + ih * 16 + orl;
            GLL(wkf + (size_t)o * 512 + tsw * 8,
                &WP[0][(w * 32 + ih * 16) * 32]);
        }
    }

    if (tid < 512) qrow[tid] = wsq[(size_t)m * 512 + tid];
    else           vrow[tid - 512] = wsv[(size_t)m * 512 + (tid - 512)];

    {   // stage X (f16): thread owns j-row l, c-block [w*32, +32)
        const float* src = dense + (size_t)b * 512 * 2048 + (size_t)ii * 64 + l;
#pragma unroll
        for (int e8 = 0; e8 < 4; ++e8) {
            const int c0 = w * 32 + e8 * 8;
            us8 pk;
#pragma unroll
            for (int e = 0; e < 8; ++e)
                pk[e] = f16bits(src[(size_t)(c0 + e) * 2048]);
            *reinterpret_cast<us8*>(&XH[l][c0]) = pk;
        }
    }
    __syncthreads();   // drains the panel-0 DMA too

    f32x4 acc[2][4];
#pragma unroll
    for (int fm = 0; fm < 2; ++fm)
#pragma unroll
        for (int fn = 0; fn < 4; ++fn) acc[fm][fn] = (f32x4){0.f, 0.f, 0.f, 0.f};

    // af read slot for this lane: (lk + h(row)) & 3, row l15 within its window
    const int aslot = (lk + ((l15 >> 1) & 3)) & 3;

    // ---- GEMM1: dn_k[o,j] = sum_c Wk[o,c] * X[c,j]
    for (int ks = 0; ks < 16; ++ks) {
        {   // prefetch next panel (last iter prefetches Wg panel 0)
            const _Float16* wsp = (ks < 15) ? (wkf + (size_t)(ks + 1) * 32) : wgf;
            _Float16* pb = WP[(ks + 1) & 1];
#pragma unroll
            for (int ih = 0; ih < 2; ++ih) {
                const int o = w * 32 + ih * 16 + orl;
                GLL(wsp + (size_t)o * 512 + tsw * 8,
                    pb + (w * 32 + ih * 16) * 32);
            }
        }
        {   // compute from WP[ks&1]
            const _Float16* pbuf = WP[ks & 1];
            f16x8 af[2], bf[4];
#pragma unroll
            for (int fm = 0; fm < 2; ++fm)
                af[fm] = *reinterpret_cast<const f16x8*>(
                    pbuf + (w * 32 + fm * 16 + l15) * 32 + aslot * 8);
#pragma unroll
            for (int fn = 0; fn < 4; ++fn)
                bf[fn] = *reinterpret_cast<const f16x8*>(&XH[fn * 16 + l15][ks * 32 + lk * 8]);
#pragma unroll
            for (int fm = 0; fm < 2; ++fm)
#pragma unroll
                for (int fn = 0; fn < 4; ++fn)
                    acc[fm][fn] = __builtin_amdgcn_mfma_f32_16x16x32_f16(af[fm], bf[fn], acc[fm][fn], 0, 0, 0);
        }
        __syncthreads();   // next panel ready, buffers safe
    }

    // ---- epilogue1: d = q - lrelu(acc*sk+bk), f16, write D over XH
#pragma unroll
    for (int fm = 0; fm < 2; ++fm) {
        const int o0 = w * 32 + fm * 16 + lk * 4;
        f32x4 skv = *reinterpret_cast<const f32x4*>(sk + o0);
        f32x4 bkv = *reinterpret_cast<const f32x4*>(bk + o0);
        f32x4 qv4 = *reinterpret_cast<const f32x4*>(&qrow[o0]);
#pragma unroll
        for (int fn = 0; fn < 4; ++fn) {
            const int j = fn * 16 + l15;
            us4 pkh;
#pragma unroll
            for (int r = 0; r < 4; ++r) {
                float h = acc[fm][fn][r] * skv[r] + bkv[r];
                h = (h >= 0.f) ? h : 0.2f * h;
                pkh[r] = f16bits(qv4[r] - h);
            }
            *reinterpret_cast<us4*>(&XH[j][o0]) = pkh;   // 8B store, o0 % 4 == 0
        }
    }
    __syncthreads();

    // ---- GEMM2: g[oo,j] = sum_o Wg[oo,o] * d[o,j]
#pragma unroll
    for (int fm = 0; fm < 2; ++fm)
#pragma unroll
        for (int fn = 0; fn < 4; ++fn) acc[fm][fn] = (f32x4){0.f, 0.f, 0.f, 0.f};

    for (int ks = 0; ks < 16; ++ks) {
        if (ks < 15) {   // prefetch next Wg panel
            const _Float16* wsp = wgf + (size_t)(ks + 1) * 32;
            _Float16* pb = WP[(ks + 1) & 1];
#pragma unroll
            for (int ih = 0; ih < 2; ++ih) {
                const int o = w * 32 + ih * 16 + orl;
                GLL(wsp + (size_t)o * 512 + tsw * 8,
                    pb + (w * 32 + ih * 16) * 32);
            }
        }
        {
            const _Float16* pbuf = WP[ks & 1];
            f16x8 af[2], bf[4];
#pragma unroll
            for (int fm = 0; fm < 2; ++fm)
                af[fm] = *reinterpret_cast<const f16x8*>(
                    pbuf + (w * 32 + fm * 16 + l15) * 32 + aslot * 8);
#pragma unroll
            for (int fn = 0; fn < 4; ++fn)
                bf[fn] = *reinterpret_cast<const f16x8*>(&XH[fn * 16 + l15][ks * 32 + lk * 8]);
#pragma unroll
            for (int fm = 0; fm < 2; ++fm)
#pragma unroll
                for (int fn = 0; fn < 4; ++fn)
                    acc[fm][fn] = __builtin_amdgcn_mfma_f32_16x16x32_f16(af[fm], bf[fn], acc[fm][fn], 0, 0, 0);
        }
        __syncthreads();
    }

    // ---- epilogue2 in place: g = lrelu(acc*sg+bg)
#pragma unroll
    for (int fm = 0; fm < 2; ++fm) {
        const int o0 = w * 32 + fm * 16 + lk * 4;
        f32x4 sgv = *reinterpret_cast<const f32x4*>(sg + o0);
        f32x4 bgv = *reinterpret_cast<const f32x4*>(bg + o0);
#pragma unroll
        for (int fn = 0; fn < 4; ++fn)
#pragma unroll
            for (int r = 0; r < 4; ++r) {
                float h = acc[fm][fn][r] * sgv[r] + bgv[r];
                acc[fm][fn][r] = (h >= 0.f) ? h : 0.2f * h;
            }
    }

    // ---- softmax over the 512 channels, per j column
    float pm[4];
#pragma unroll
    for (int fn = 0; fn < 4; ++fn) {
        float mx = -1e30f;
#pragma unroll
        for (int fm = 0; fm < 2; ++fm)
#pragma unroll
            for (int r = 0; r < 4; ++r) mx = fmaxf(mx, acc[fm][fn][r]);
        mx = fmaxf(mx, __shfl_xor(mx, 16, 64));
        mx = fmaxf(mx, __shfl_xor(mx, 32, 64));
        pm[fn] = mx;
    }
    if (l < 16) {
#pragma unroll
        for (int fn = 0; fn < 4; ++fn) wredA[w][fn * 16 + l] = pm[fn];
    }
    __syncthreads();

    float jmax[4];
#pragma unroll
    for (int fn = 0; fn < 4; ++fn) {
        float mx = wredA[0][fn * 16 + l15];
#pragma unroll
        for (int ww = 1; ww < 16; ++ww) mx = fmaxf(mx, wredA[ww][fn * 16 + l15]);
        jmax[fn] = mx;
    }

    float ps[4] = {0.f, 0.f, 0.f, 0.f};
#pragma unroll
    for (int fm = 0; fm < 2; ++fm)
#pragma unroll
        for (int fn = 0; fn < 4; ++fn)
#pragma unroll
            for (int r = 0; r < 4; ++r) {
                float e = __expf(acc[fm][fn][r] - jmax[fn]);
                acc[fm][fn][r] = e;
                ps[fn] += e;
            }
#pragma unroll
    for (int fn = 0; fn < 4; ++fn) {
        ps[fn] += __shfl_xor(ps[fn], 16, 64);
        ps[fn] += __shfl_xor(ps[fn], 32, 64);
    }
    if (l < 16) {
#pragma unroll
        for (int fn = 0; fn < 4; ++fn) wredB[w][fn * 16 + l] = ps[fn];
    }
    __syncthreads();

    float rinv[4];
#pragma unroll
    for (int fn = 0; fn < 4; ++fn) {
        float s = 0.f;
#pragma unroll
        for (int ww = 0; ww < 16; ++ww) s += wredB[ww][fn * 16 + l15];
        rinv[fn] = 1.f / s;
    }

    // ---- out[b,oo,i] = sp_v[oo] * sum_j coef[oo,j]   (FP32 store)
#pragma unroll
    for (int fm = 0; fm < 2; ++fm) {
#pragma unroll
        for (int r = 0; r < 4; ++r) {
            float tsum = 0.f;
#pragma unroll
            for (int fn = 0; fn < 4; ++fn) tsum += acc[fm][fn][r] * rinv[fn];
            tsum += __shfl_xor(tsum, 1, 64);
            tsum += __shfl_xor(tsum, 2, 64);
            tsum += __shfl_xor(tsum, 4, 64);
            tsum += __shfl_xor(tsum, 8, 64);
            if (l15 == 0) {
                int oo = w * 32 + fm * 16 + lk * 4 + r;
                out[((size_t)b * 512 + oo) * 32 + ii] = vrow[oo] * tsum;
            }
        }
    }
}

// ---------------------------------------------------------------------------
extern "C" void kernel_launch(void* const* d_in, const int* in_sizes, int n_in,
                              void* d_out, int out_size, void* d_ws, size_t ws_size,
                              hipStream_t stream) {
    const float* sparse = (const float*)d_in[0];
    const float* dense  = (const float*)d_in[1];
    const float* Wq = (const float*)d_in[2];
    const float* sq = (const float*)d_in[3];
    const float* bq = (const float*)d_in[4];
    const float* Wk = (const float*)d_in[5];
    const float* sk = (const float*)d_in[6];
    const float* bk = (const float*)d_in[7];
    const float* Wv = (const float*)d_in[8];
    const float* sv = (const float*)d_in[9];
    const float* bv = (const float*)d_in[10];
    const float* Wg = (const float*)d_in[11];
    const float* sg = (const float*)d_in[12];
    const float* bg = (const float*)d_in[13];
    float* out = (float*)d_out;

    // workspace: [sp_q f32 2MB][sp_v f32 2MB][Wk f16 512KB][Wg f16 512KB]
    float* wsq = (float*)d_ws;
    float* wsv = wsq + 1024 * 512;
    _Float16* wkf = (_Float16*)(wsv + 1024 * 512);
    _Float16* wgf = wkf + 512 * 512;

    cvt_weights<<<512, 256, 0, stream>>>(Wk, Wg, wkf, wgf);
    qv_gemm<<<dim3(16, 8, 2), 256, 0, stream>>>(sparse, Wq, sq, bq, Wv, sv, bv, wsq, wsv);
    fused_attn<<<1024, 1024, 0, stream>>>(dense, wkf, wgf, wsq, wsv, sk, bk, sg, bg, out);
}

// Round 13
// 179.920 us; speedup vs baseline: 1.8420x; 1.0633x over previous
//
#include <hip/hip_runtime.h>
#include <hip/hip_bf16.h>

#define EMB 512
#define NSTK 32
#define NPNT 64
#define BSZ 32

typedef __attribute__((ext_vector_type(8))) _Float16 f16x8;
typedef __attribute__((ext_vector_type(4))) float f32x4;
typedef __attribute__((ext_vector_type(4))) unsigned short us4;
typedef __attribute__((ext_vector_type(8))) unsigned short us8;

static __device__ __forceinline__ unsigned short f16bits(float x) {
    _Float16 h = (_Float16)x;
    return *reinterpret_cast<unsigned short*>(&h);
}

// async global->LDS DMA: dest = wave-uniform lds base + lane*16 (m104 semantics)
#define GLL(gsrc, ldst)                                                         \
    __builtin_amdgcn_global_load_lds(                                           \
        (const __attribute__((address_space(1))) void*)(gsrc),                  \
        (__attribute__((address_space(3))) void*)(ldst), 16, 0, 0)

#define SBAR() __builtin_amdgcn_s_barrier()

// ---------------------------------------------------------------------------
// Kernel A: convert Wk and Wg (fp32 512x512) to f16.
// ---------------------------------------------------------------------------
__global__ void cvt_weights(const float* __restrict__ wk,
                            const float* __restrict__ wg,
                            _Float16* __restrict__ wkf,
                            _Float16* __restrict__ wgf) {
    int idx = blockIdx.x * blockDim.x + threadIdx.x;   // 0..131071, 4 elems each
    const float* src;
    _Float16* dst;
    int k;
    if (idx < 65536) { src = wk; dst = wkf; k = idx; }
    else             { src = wg; dst = wgf; k = idx - 65536; }
    f32x4 v = *reinterpret_cast<const f32x4*>(src + (size_t)k * 4);
    us4 o;
#pragma unroll
    for (int e = 0; e < 4; ++e) o[e] = f16bits(v[e]);
    *reinterpret_cast<us4*>(dst + (size_t)k * 4) = o;
}

// ---------------------------------------------------------------------------
// Kernel B: sp_q / sp_v — fp32 GEMM (unchanged).
// ---------------------------------------------------------------------------
__global__ __launch_bounds__(256)
void qv_gemm(const float* __restrict__ sparse,
             const float* __restrict__ Wq, const float* __restrict__ sq, const float* __restrict__ bq,
             const float* __restrict__ Wv, const float* __restrict__ sv, const float* __restrict__ bv,
             float* __restrict__ outq, float* __restrict__ outv) {
    const float* W  = (blockIdx.z == 0) ? Wq : Wv;
    const float* sc = (blockIdx.z == 0) ? sq : sv;
    const float* bi = (blockIdx.z == 0) ? bq : bv;
    float* orow     = (blockIdx.z == 0) ? outq : outv;

    __shared__ float Wt[64][33];
    __shared__ float St[32][65];

    const int m0 = blockIdx.x * 64;
    const int o0 = blockIdx.y * 64;
    const int t  = threadIdx.x;
    const int ty = t >> 4, tx = t & 15;

    float acc[4][4] = {};

    for (int k0 = 0; k0 < 512; k0 += 32) {
        {
            int ol = t >> 2, kl = (t & 3) * 8;
            const float* p = W + (size_t)(o0 + ol) * 512 + k0 + kl;
            f32x4 v0 = *reinterpret_cast<const f32x4*>(p);
            f32x4 v1 = *reinterpret_cast<const f32x4*>(p + 4);
#pragma unroll
            for (int e = 0; e < 4; ++e) { Wt[ol][kl + e] = v0[e]; Wt[ol][kl + 4 + e] = v1[e]; }
        }
        {
            int kl = t >> 3, ml = (t & 7) * 8;
            int mm = m0 + ml;
            int bb = mm >> 5, iidx = mm & 31;
            const float* p = sparse + (size_t)bb * 16384 + (size_t)(k0 + kl) * 32 + iidx;
            f32x4 v0 = *reinterpret_cast<const f32x4*>(p);
            f32x4 v1 = *reinterpret_cast<const f32x4*>(p + 4);
#pragma unroll
            for (int e = 0; e < 4; ++e) { St[kl][ml + e] = v0[e]; St[kl][ml + 4 + e] = v1[e]; }
        }
        __syncthreads();
#pragma unroll
        for (int kk = 0; kk < 32; ++kk) {
            float av[4], bvv[4];
#pragma unroll
            for (int e = 0; e < 4; ++e) av[e]  = Wt[ty * 4 + e][kk];
#pragma unroll
            for (int e = 0; e < 4; ++e) bvv[e] = St[kk][tx * 4 + e];
#pragma unroll
            for (int a = 0; a < 4; ++a)
#pragma unroll
                for (int bb2 = 0; bb2 < 4; ++bb2) acc[a][bb2] += av[a] * bvv[bb2];
        }
        __syncthreads();
    }
#pragma unroll
    for (int ae = 0; ae < 4; ++ae) {
        int o = o0 + ty * 4 + ae;
        float s = sc[o], bb2 = bi[o];
#pragma unroll
        for (int be = 0; be < 4; ++be) {
            int mm = m0 + tx * 4 + be;
            float h = acc[ae][be] * s + bb2;
            h = (h >= 0.f) ? h : 0.2f * h;
            orow[(size_t)mm * 512 + o] = h;
        }
    }
}

// ---------------------------------------------------------------------------
// Kernel C: fused main. One WG (16 waves, 1024 thr) per (b,i).
// R12 + counted-vmcnt pipeline (T4): each wave DMAs exactly the panel rows it
// reads, so `s_waitcnt vmcnt(2)` (its own prev-panel GLLs) replaces the full
// barrier drain; raw s_barrier handles only the WAR buffer-reuse hazard.
// ---------------------------------------------------------------------------
__global__ __launch_bounds__(1024, 4)
void fused_attn(const float* __restrict__ dense,
                const _Float16* __restrict__ wkf,
                const _Float16* __restrict__ wgf,
                const float* __restrict__ wsq,
                const float* __restrict__ wsv,
                const float* __restrict__ sk, const float* __restrict__ bk,
                const float* __restrict__ sg, const float* __restrict__ bg,
                float* __restrict__ out) {
    __shared__ __align__(16) _Float16 XH[64][520];     // 66.5 KB, X -> D (f16)
    __shared__ __align__(16) _Float16 WP[2][512 * 32]; // 2 x 32 KB weight panels
    __shared__ __align__(16) float qrow[512];
    __shared__ __align__(16) float vrow[512];
    __shared__ float wredA[16][64];
    __shared__ float wredB[16][64];

    const int m   = blockIdx.x;        // 0..1023
    const int b   = m >> 5, ii = m & 31;
    const int tid = threadIdx.x;       // 0..1023
    const int w   = tid >> 6;          // wave 0..15
    const int l   = tid & 63;
    const int l15 = l & 15;
    const int lk  = l >> 4;            // 0..3

    // swizzled k-chunk this lane DMAs (m173 pre-swizzled source, as R12)
    const int tsw = ((l & 3) - ((l >> 3) & 3)) & 3;
    const int orl = l >> 2;

    // ---- prologue: DMA Wk panel 0 into WP[0] (overlaps X staging)
    {
#pragma unroll
        for (int ih = 0; ih < 2; ++ih) {
            const int o = w * 32 + ih * 16 + orl;
            GLL(wkf + (size_t)o * 512 + tsw * 8,
                &WP[0][(w * 32 + ih * 16) * 32]);
        }
    }

    if (tid < 512) qrow[tid] = wsq[(size_t)m * 512 + tid];
    else           vrow[tid - 512] = wsv[(size_t)m * 512 + (tid - 512)];

    {   // stage X (f16): thread owns j-row l, c-block [w*32, +32)
        const float* src = dense + (size_t)b * 512 * 2048 + (size_t)ii * 64 + l;
#pragma unroll
        for (int e8 = 0; e8 < 4; ++e8) {
            const int c0 = w * 32 + e8 * 8;
            us8 pk;
#pragma unroll
            for (int e = 0; e < 8; ++e)
                pk[e] = f16bits(src[(size_t)(c0 + e) * 2048]);
            *reinterpret_cast<us8*>(&XH[l][c0]) = pk;
        }
    }
    __syncthreads();   // full drain once: X staged + panel 0 resident

    f32x4 acc[2][4];
#pragma unroll
    for (int fm = 0; fm < 2; ++fm)
#pragma unroll
        for (int fn = 0; fn < 4; ++fn) acc[fm][fn] = (f32x4){0.f, 0.f, 0.f, 0.f};

    const int aslot = (lk + ((l15 >> 1) & 3)) & 3;

    // ---- GEMM1: dn_k[o,j] = sum_c Wk[o,c] * X[c,j]
    for (int ks = 0; ks < 16; ++ks) {
        {   // issue next panel (last iter issues Wg panel 0)
            const _Float16* wsp = (ks < 15) ? (wkf + (size_t)(ks + 1) * 32) : wgf;
            _Float16* pb = WP[(ks + 1) & 1];
#pragma unroll
            for (int ih = 0; ih < 2; ++ih) {
                const int o = w * 32 + ih * 16 + orl;
                GLL(wsp + (size_t)o * 512 + tsw * 8,
                    pb + (w * 32 + ih * 16) * 32);
            }
        }
        asm volatile("s_waitcnt vmcnt(2)" ::: "memory");   // panel ks landed
        {   // compute from WP[ks&1]
            const _Float16* pbuf = WP[ks & 1];
            f16x8 af[2], bf[4];
#pragma unroll
            for (int fm = 0; fm < 2; ++fm)
                af[fm] = *reinterpret_cast<const f16x8*>(
                    pbuf + (w * 32 + fm * 16 + l15) * 32 + aslot * 8);
#pragma unroll
            for (int fn = 0; fn < 4; ++fn)
                bf[fn] = *reinterpret_cast<const f16x8*>(&XH[fn * 16 + l15][ks * 32 + lk * 8]);
#pragma unroll
            for (int fm = 0; fm < 2; ++fm)
#pragma unroll
                for (int fn = 0; fn < 4; ++fn)
                    acc[fm][fn] = __builtin_amdgcn_mfma_f32_16x16x32_f16(af[fm], bf[fn], acc[fm][fn], 0, 0, 0);
        }
        SBAR();   // WAR: all waves done reading WP[ks&1] before next GLL reuses it
    }

    // ---- epilogue1: d = q - lrelu(acc*sk+bk), f16, write D over XH
#pragma unroll
    for (int fm = 0; fm < 2; ++fm) {
        const int o0 = w * 32 + fm * 16 + lk * 4;
        f32x4 skv = *reinterpret_cast<const f32x4*>(sk + o0);
        f32x4 bkv = *reinterpret_cast<const f32x4*>(bk + o0);
        f32x4 qv4 = *reinterpret_cast<const f32x4*>(&qrow[o0]);
#pragma unroll
        for (int fn = 0; fn < 4; ++fn) {
            const int j = fn * 16 + l15;
            us4 pkh;
#pragma unroll
            for (int r = 0; r < 4; ++r) {
                float h = acc[fm][fn][r] * skv[r] + bkv[r];
                h = (h >= 0.f) ? h : 0.2f * h;
                pkh[r] = f16bits(qv4[r] - h);
            }
            *reinterpret_cast<us4*>(&XH[j][o0]) = pkh;   // 8B store, o0 % 4 == 0
        }
    }
    asm volatile("s_waitcnt lgkmcnt(0)" ::: "memory");
    SBAR();   // D visible to all waves (Wg panel-0 DMA still in flight - OK)

    // ---- GEMM2: g[oo,j] = sum_o Wg[oo,o] * d[o,j]
#pragma unroll
    for (int fm = 0; fm < 2; ++fm)
#pragma unroll
        for (int fn = 0; fn < 4; ++fn) acc[fm][fn] = (f32x4){0.f, 0.f, 0.f, 0.f};

    for (int ks = 0; ks < 16; ++ks) {
        if (ks < 15) {   // issue next Wg panel
            const _Float16* wsp = wgf + (size_t)(ks + 1) * 32;
            _Float16* pb = WP[(ks + 1) & 1];
#pragma unroll
            for (int ih = 0; ih < 2; ++ih) {
                const int o = w * 32 + ih * 16 + orl;
                GLL(wsp + (size_t)o * 512 + tsw * 8,
                    pb + (w * 32 + ih * 16) * 32);
            }
            asm volatile("s_waitcnt vmcnt(2)" ::: "memory");
        } else {
            asm volatile("s_waitcnt vmcnt(0)" ::: "memory");
        }
        {
            const _Float16* pbuf = WP[ks & 1];
            f16x8 af[2], bf[4];
#pragma unroll
            for (int fm = 0; fm < 2; ++fm)
                af[fm] = *reinterpret_cast<const f16x8*>(
                    pbuf + (w * 32 + fm * 16 + l15) * 32 + aslot * 8);
#pragma unroll
            for (int fn = 0; fn < 4; ++fn)
                bf[fn] = *reinterpret_cast<const f16x8*>(&XH[fn * 16 + l15][ks * 32 + lk * 8]);
#pragma unroll
            for (int fm = 0; fm < 2; ++fm)
#pragma unroll
                for (int fn = 0; fn < 4; ++fn)
                    acc[fm][fn] = __builtin_amdgcn_mfma_f32_16x16x32_f16(af[fm], bf[fn], acc[fm][fn], 0, 0, 0);
        }
        SBAR();
    }

    // ---- epilogue2 in place: g = lrelu(acc*sg+bg)
#pragma unroll
    for (int fm = 0; fm < 2; ++fm) {
        const int o0 = w * 32 + fm * 16 + lk * 4;
        f32x4 sgv = *reinterpret_cast<const f32x4*>(sg + o0);
        f32x4 bgv = *reinterpret_cast<const f32x4*>(bg + o0);
#pragma unroll
        for (int fn = 0; fn < 4; ++fn)
#pragma unroll
            for (int r = 0; r < 4; ++r) {
                float h = acc[fm][fn][r] * sgv[r] + bgv[r];
                acc[fm][fn][r] = (h >= 0.f) ? h : 0.2f * h;
            }
    }

    // ---- softmax over the 512 channels, per j column
    float pm[4];
#pragma unroll
    for (int fn = 0; fn < 4; ++fn) {
        float mx = -1e30f;
#pragma unroll
        for (int fm = 0; fm < 2; ++fm)
#pragma unroll
            for (int r = 0; r < 4; ++r) mx = fmaxf(mx, acc[fm][fn][r]);
        mx = fmaxf(mx, __shfl_xor(mx, 16, 64));
        mx = fmaxf(mx, __shfl_xor(mx, 32, 64));
        pm[fn] = mx;
    }
    if (l < 16) {
#pragma unroll
        for (int fn = 0; fn < 4; ++fn) wredA[w][fn * 16 + l] = pm[fn];
    }
    __syncthreads();

    float jmax[4];
#pragma unroll
    for (int fn = 0; fn < 4; ++fn) {
        float mx = wredA[0][fn * 16 + l15];
#pragma unroll
        for (int ww = 1; ww < 16; ++ww) mx = fmaxf(mx, wredA[ww][fn * 16 + l15]);
        jmax[fn] = mx;
    }

    float ps[4] = {0.f, 0.f, 0.f, 0.f};
#pragma unroll
    for (int fm = 0; fm < 2; ++fm)
#pragma unroll
        for (int fn = 0; fn < 4; ++fn)
#pragma unroll
            for (int r = 0; r < 4; ++r) {
                float e = __expf(acc[fm][fn][r] - jmax[fn]);
                acc[fm][fn][r] = e;
                ps[fn] += e;
            }
#pragma unroll
    for (int fn = 0; fn < 4; ++fn) {
        ps[fn] += __shfl_xor(ps[fn], 16, 64);
        ps[fn] += __shfl_xor(ps[fn], 32, 64);
    }
    if (l < 16) {
#pragma unroll
        for (int fn = 0; fn < 4; ++fn) wredB[w][fn * 16 + l] = ps[fn];
    }
    __syncthreads();

    float rinv[4];
#pragma unroll
    for (int fn = 0; fn < 4; ++fn) {
        float s = 0.f;
#pragma unroll
        for (int ww = 0; ww < 16; ++ww) s += wredB[ww][fn * 16 + l15];
        rinv[fn] = 1.f / s;
    }

    // ---- out[b,oo,i] = sp_v[oo] * sum_j coef[oo,j]   (FP32 store)
#pragma unroll
    for (int fm = 0; fm < 2; ++fm) {
#pragma unroll
        for (int r = 0; r < 4; ++r) {
            float tsum = 0.f;
#pragma unroll
            for (int fn = 0; fn < 4; ++fn) tsum += acc[fm][fn][r] * rinv[fn];
            tsum += __shfl_xor(tsum, 1, 64);
            tsum += __shfl_xor(tsum, 2, 64);
            tsum += __shfl_xor(tsum, 4, 64);
            tsum += __shfl_xor(tsum, 8, 64);
            if (l15 == 0) {
                int oo = w * 32 + fm * 16 + lk * 4 + r;
                out[((size_t)b * 512 + oo) * 32 + ii] = vrow[oo] * tsum;
            }
        }
    }
}

// ---------------------------------------------------------------------------
extern "C" void kernel_launch(void* const* d_in, const int* in_sizes, int n_in,
                              void* d_out, int out_size, void* d_ws, size_t ws_size,
                              hipStream_t stream) {
    const float* sparse = (const float*)d_in[0];
    const float* dense  = (const float*)d_in[1];
    const float* Wq = (const float*)d_in[2];
    const float* sq = (const float*)d_in[3];
    const float* bq = (const float*)d_in[4];
    const float* Wk = (const float*)d_in[5];
    const float* sk = (const float*)d_in[6];
    const float* bk = (const float*)d_in[7];
    const float* Wv = (const float*)d_in[8];
    const float* sv = (const float*)d_in[9];
    const float* bv = (const float*)d_in[10];
    const float* Wg = (const float*)d_in[11];
    const float* sg = (const float*)d_in[12];
    const float* bg = (const float*)d_in[13];
    float* out = (float*)d_out;

    // workspace: [sp_q f32 2MB][sp_v f32 2MB][Wk f16 512KB][Wg f16 512KB]
    float* wsq = (float*)d_ws;
    float* wsv = wsq + 1024 * 512;
    _Float16* wkf = (_Float16*)(wsv + 1024 * 512);
    _Float16* wgf = wkf + 512 * 512;

    cvt_weights<<<512, 256, 0, stream>>>(Wk, Wg, wkf, wgf);
    qv_gemm<<<dim3(16, 8, 2), 256, 0, stream>>>(sparse, Wq, sq, bq, Wv, sv, bv, wsq, wsv);
    fused_attn<<<1024, 1024, 0, stream>>>(dense, wkf, wgf, wsq, wsv, sk, bk, sg, bg, out);
}

// Round 14
// 155.666 us; speedup vs baseline: 2.1290x; 1.1558x over previous
//
#include <hip/hip_runtime.h>
#include <hip/hip_bf16.h>

#define EMB 512
#define NSTK 32
#define NPNT 64
#define BSZ 32

typedef __attribute__((ext_vector_type(8))) _Float16 f16x8;
typedef __attribute__((ext_vector_type(4))) float f32x4;
typedef __attribute__((ext_vector_type(4))) unsigned short us4;
typedef __attribute__((ext_vector_type(8))) unsigned short us8;

static __device__ __forceinline__ unsigned short f16bits(float x) {
    _Float16 h = (_Float16)x;
    return *reinterpret_cast<unsigned short*>(&h);
}

// async global->LDS DMA: dest = wave-uniform lds base + lane*16 (m104 semantics)
#define GLL(gsrc, ldst)                                                         \
    __builtin_amdgcn_global_load_lds(                                           \
        (const __attribute__((address_space(1))) void*)(gsrc),                  \
        (__attribute__((address_space(3))) void*)(ldst), 16, 0, 0)

#define SBAR() __builtin_amdgcn_s_barrier()

// ---------------------------------------------------------------------------
// Kernel A: convert Wk and Wg (fp32 512x512) to f16.
// ---------------------------------------------------------------------------
__global__ void cvt_weights(const float* __restrict__ wk,
                            const float* __restrict__ wg,
                            _Float16* __restrict__ wkf,
                            _Float16* __restrict__ wgf) {
    int idx = blockIdx.x * blockDim.x + threadIdx.x;   // 0..131071, 4 elems each
    const float* src;
    _Float16* dst;
    int k;
    if (idx < 65536) { src = wk; dst = wkf; k = idx; }
    else             { src = wg; dst = wgf; k = idx - 65536; }
    f32x4 v = *reinterpret_cast<const f32x4*>(src + (size_t)k * 4);
    us4 o;
#pragma unroll
    for (int e = 0; e < 4; ++e) o[e] = f16bits(v[e]);
    *reinterpret_cast<us4*>(dst + (size_t)k * 4) = o;
}

// ---------------------------------------------------------------------------
// Kernel B: sp_q / sp_v — fp32 GEMM (unchanged).
// ---------------------------------------------------------------------------
__global__ __launch_bounds__(256)
void qv_gemm(const float* __restrict__ sparse,
             const float* __restrict__ Wq, const float* __restrict__ sq, const float* __restrict__ bq,
             const float* __restrict__ Wv, const float* __restrict__ sv, const float* __restrict__ bv,
             float* __restrict__ outq, float* __restrict__ outv) {
    const float* W  = (blockIdx.z == 0) ? Wq : Wv;
    const float* sc = (blockIdx.z == 0) ? sq : sv;
    const float* bi = (blockIdx.z == 0) ? bq : bv;
    float* orow     = (blockIdx.z == 0) ? outq : outv;

    __shared__ float Wt[64][33];
    __shared__ float St[32][65];

    const int m0 = blockIdx.x * 64;
    const int o0 = blockIdx.y * 64;
    const int t  = threadIdx.x;
    const int ty = t >> 4, tx = t & 15;

    float acc[4][4] = {};

    for (int k0 = 0; k0 < 512; k0 += 32) {
        {
            int ol = t >> 2, kl = (t & 3) * 8;
            const float* p = W + (size_t)(o0 + ol) * 512 + k0 + kl;
            f32x4 v0 = *reinterpret_cast<const f32x4*>(p);
            f32x4 v1 = *reinterpret_cast<const f32x4*>(p + 4);
#pragma unroll
            for (int e = 0; e < 4; ++e) { Wt[ol][kl + e] = v0[e]; Wt[ol][kl + 4 + e] = v1[e]; }
        }
        {
            int kl = t >> 3, ml = (t & 7) * 8;
            int mm = m0 + ml;
            int bb = mm >> 5, iidx = mm & 31;
            const float* p = sparse + (size_t)bb * 16384 + (size_t)(k0 + kl) * 32 + iidx;
            f32x4 v0 = *reinterpret_cast<const f32x4*>(p);
            f32x4 v1 = *reinterpret_cast<const f32x4*>(p + 4);
#pragma unroll
            for (int e = 0; e < 4; ++e) { St[kl][ml + e] = v0[e]; St[kl][ml + 4 + e] = v1[e]; }
        }
        __syncthreads();
#pragma unroll
        for (int kk = 0; kk < 32; ++kk) {
            float av[4], bvv[4];
#pragma unroll
            for (int e = 0; e < 4; ++e) av[e]  = Wt[ty * 4 + e][kk];
#pragma unroll
            for (int e = 0; e < 4; ++e) bvv[e] = St[kk][tx * 4 + e];
#pragma unroll
            for (int a = 0; a < 4; ++a)
#pragma unroll
                for (int bb2 = 0; bb2 < 4; ++bb2) acc[a][bb2] += av[a] * bvv[bb2];
        }
        __syncthreads();
    }
#pragma unroll
    for (int ae = 0; ae < 4; ++ae) {
        int o = o0 + ty * 4 + ae;
        float s = sc[o], bb2 = bi[o];
#pragma unroll
        for (int be = 0; be < 4; ++be) {
            int mm = m0 + tx * 4 + be;
            float h = acc[ae][be] * s + bb2;
            h = (h >= 0.f) ? h : 0.2f * h;
            orow[(size_t)mm * 512 + o] = h;
        }
    }
}

// ---------------------------------------------------------------------------
// Kernel C: fused main. One WG (16 waves, 1024 thr) per (b,i).
// KEY CHANGE vs R13: the K-loops are BARRIER-FREE. Each wave's WP region
// (rows [w*32,w*32+32)) is private — it DMAs and reads only its own rows, so
// panel readiness is per-wave (vmcnt(2)) and WP WAR is per-wave-ordered
// (ds_reads retire via lgkmcnt before the next GLL issues). Barriers remain
// only at the true cross-wave points: post-X-stage and post-epilogue1.
// ---------------------------------------------------------------------------
__global__ __launch_bounds__(1024, 4)
void fused_attn(const float* __restrict__ dense,
                const _Float16* __restrict__ wkf,
                const _Float16* __restrict__ wgf,
                const float* __restrict__ wsq,
                const float* __restrict__ wsv,
                const float* __restrict__ sk, const float* __restrict__ bk,
                const float* __restrict__ sg, const float* __restrict__ bg,
                float* __restrict__ out) {
    __shared__ __align__(16) _Float16 XH[64][520];     // 66.5 KB, X -> D (f16)
    __shared__ __align__(16) _Float16 WP[2][512 * 32]; // 2 x 32 KB weight panels
    __shared__ __align__(16) float qrow[512];
    __shared__ __align__(16) float vrow[512];
    __shared__ float wredA[16][64];
    __shared__ float wredB[16][64];

    const int m   = blockIdx.x;        // 0..1023
    const int b   = m >> 5, ii = m & 31;
    const int tid = threadIdx.x;       // 0..1023
    const int w   = tid >> 6;          // wave 0..15
    const int l   = tid & 63;
    const int l15 = l & 15;
    const int lk  = l >> 4;            // 0..3

    // swizzled k-chunk this lane DMAs (m173 pre-swizzled source, as R12)
    const int tsw = ((l & 3) - ((l >> 3) & 3)) & 3;
    const int orl = l >> 2;

    // ---- prologue: DMA Wk panel 0 into WP[0] (overlaps X staging)
    {
#pragma unroll
        for (int ih = 0; ih < 2; ++ih) {
            const int o = w * 32 + ih * 16 + orl;
            GLL(wkf + (size_t)o * 512 + tsw * 8,
                &WP[0][(w * 32 + ih * 16) * 32]);
        }
    }

    if (tid < 512) qrow[tid] = wsq[(size_t)m * 512 + tid];
    else           vrow[tid - 512] = wsv[(size_t)m * 512 + (tid - 512)];

    {   // stage X (f16): thread owns j-row l, c-block [w*32, +32)
        const float* src = dense + (size_t)b * 512 * 2048 + (size_t)ii * 64 + l;
#pragma unroll
        for (int e8 = 0; e8 < 4; ++e8) {
            const int c0 = w * 32 + e8 * 8;
            us8 pk;
#pragma unroll
            for (int e = 0; e < 8; ++e)
                pk[e] = f16bits(src[(size_t)(c0 + e) * 2048]);
            *reinterpret_cast<us8*>(&XH[l][c0]) = pk;
        }
    }
    __syncthreads();   // full drain once: X staged + panel 0 resident

    f32x4 acc[2][4];
#pragma unroll
    for (int fm = 0; fm < 2; ++fm)
#pragma unroll
        for (int fn = 0; fn < 4; ++fn) acc[fm][fn] = (f32x4){0.f, 0.f, 0.f, 0.f};

    const int aslot = (lk + ((l15 >> 1) & 3)) & 3;

    // ---- GEMM1: dn_k[o,j] = sum_c Wk[o,c] * X[c,j]   (barrier-free K-loop)
    for (int ks = 0; ks < 16; ++ks) {
        {   // issue next panel (last iter issues Wg panel 0)
            const _Float16* wsp = (ks < 15) ? (wkf + (size_t)(ks + 1) * 32) : wgf;
            _Float16* pb = WP[(ks + 1) & 1];
#pragma unroll
            for (int ih = 0; ih < 2; ++ih) {
                const int o = w * 32 + ih * 16 + orl;
                GLL(wsp + (size_t)o * 512 + tsw * 8,
                    pb + (w * 32 + ih * 16) * 32);
            }
        }
        asm volatile("s_waitcnt vmcnt(2)" ::: "memory");   // own panel ks landed
        {   // compute from WP[ks&1]
            const _Float16* pbuf = WP[ks & 1];
            f16x8 af[2], bf[4];
#pragma unroll
            for (int fm = 0; fm < 2; ++fm)
                af[fm] = *reinterpret_cast<const f16x8*>(
                    pbuf + (w * 32 + fm * 16 + l15) * 32 + aslot * 8);
#pragma unroll
            for (int fn = 0; fn < 4; ++fn)
                bf[fn] = *reinterpret_cast<const f16x8*>(&XH[fn * 16 + l15][ks * 32 + lk * 8]);
#pragma unroll
            for (int fm = 0; fm < 2; ++fm)
#pragma unroll
                for (int fn = 0; fn < 4; ++fn)
                    acc[fm][fn] = __builtin_amdgcn_mfma_f32_16x16x32_f16(af[fm], bf[fn], acc[fm][fn], 0, 0, 0);
        }
        // no barrier: WP rows are wave-private; XH is read-only here
    }

    // ---- epilogue1: d = q - lrelu(acc*sk+bk), f16, write D over XH
#pragma unroll
    for (int fm = 0; fm < 2; ++fm) {
        const int o0 = w * 32 + fm * 16 + lk * 4;
        f32x4 skv = *reinterpret_cast<const f32x4*>(sk + o0);
        f32x4 bkv = *reinterpret_cast<const f32x4*>(bk + o0);
        f32x4 qv4 = *reinterpret_cast<const f32x4*>(&qrow[o0]);
#pragma unroll
        for (int fn = 0; fn < 4; ++fn) {
            const int j = fn * 16 + l15;
            us4 pkh;
#pragma unroll
            for (int r = 0; r < 4; ++r) {
                float h = acc[fm][fn][r] * skv[r] + bkv[r];
                h = (h >= 0.f) ? h : 0.2f * h;
                pkh[r] = f16bits(qv4[r] - h);
            }
            *reinterpret_cast<us4*>(&XH[j][o0]) = pkh;   // 8B store, o0 % 4 == 0
        }
    }
    asm volatile("s_waitcnt lgkmcnt(0)" ::: "memory");
    SBAR();   // D visible to all waves (Wg panel-0 DMA still in flight - OK)

    // ---- GEMM2: g[oo,j] = sum_o Wg[oo,o] * d[o,j]   (barrier-free K-loop)
#pragma unroll
    for (int fm = 0; fm < 2; ++fm)
#pragma unroll
        for (int fn = 0; fn < 4; ++fn) acc[fm][fn] = (f32x4){0.f, 0.f, 0.f, 0.f};

    for (int ks = 0; ks < 16; ++ks) {
        if (ks < 15) {   // issue next Wg panel
            const _Float16* wsp = wgf + (size_t)(ks + 1) * 32;
            _Float16* pb = WP[(ks + 1) & 1];
#pragma unroll
            for (int ih = 0; ih < 2; ++ih) {
                const int o = w * 32 + ih * 16 + orl;
                GLL(wsp + (size_t)o * 512 + tsw * 8,
                    pb + (w * 32 + ih * 16) * 32);
            }
            asm volatile("s_waitcnt vmcnt(2)" ::: "memory");
        } else {
            asm volatile("s_waitcnt vmcnt(0)" ::: "memory");
        }
        {
            const _Float16* pbuf = WP[ks & 1];
            f16x8 af[2], bf[4];
#pragma unroll
            for (int fm = 0; fm < 2; ++fm)
                af[fm] = *reinterpret_cast<const f16x8*>(
                    pbuf + (w * 32 + fm * 16 + l15) * 32 + aslot * 8);
#pragma unroll
            for (int fn = 0; fn < 4; ++fn)
                bf[fn] = *reinterpret_cast<const f16x8*>(&XH[fn * 16 + l15][ks * 32 + lk * 8]);
#pragma unroll
            for (int fm = 0; fm < 2; ++fm)
#pragma unroll
                for (int fn = 0; fn < 4; ++fn)
                    acc[fm][fn] = __builtin_amdgcn_mfma_f32_16x16x32_f16(af[fm], bf[fn], acc[fm][fn], 0, 0, 0);
        }
        // no barrier: WP rows wave-private, XH read-only
    }

    // ---- epilogue2 in place: g = lrelu(acc*sg+bg)
#pragma unroll
    for (int fm = 0; fm < 2; ++fm) {
        const int o0 = w * 32 + fm * 16 + lk * 4;
        f32x4 sgv = *reinterpret_cast<const f32x4*>(sg + o0);
        f32x4 bgv = *reinterpret_cast<const f32x4*>(bg + o0);
#pragma unroll
        for (int fn = 0; fn < 4; ++fn)
#pragma unroll
            for (int r = 0; r < 4; ++r) {
                float h = acc[fm][fn][r] * sgv[r] + bgv[r];
                acc[fm][fn][r] = (h >= 0.f) ? h : 0.2f * h;
            }
    }

    // ---- softmax over the 512 channels, per j column
    float pm[4];
#pragma unroll
    for (int fn = 0; fn < 4; ++fn) {
        float mx = -1e30f;
#pragma unroll
        for (int fm = 0; fm < 2; ++fm)
#pragma unroll
            for (int r = 0; r < 4; ++r) mx = fmaxf(mx, acc[fm][fn][r]);
        mx = fmaxf(mx, __shfl_xor(mx, 16, 64));
        mx = fmaxf(mx, __shfl_xor(mx, 32, 64));
        pm[fn] = mx;
    }
    if (l < 16) {
#pragma unroll
        for (int fn = 0; fn < 4; ++fn) wredA[w][fn * 16 + l] = pm[fn];
    }
    __syncthreads();

    float jmax[4];
#pragma unroll
    for (int fn = 0; fn < 4; ++fn) {
        float mx = wredA[0][fn * 16 + l15];
#pragma unroll
        for (int ww = 1; ww < 16; ++ww) mx = fmaxf(mx, wredA[ww][fn * 16 + l15]);
        jmax[fn] = mx;
    }

    float ps[4] = {0.f, 0.f, 0.f, 0.f};
#pragma unroll
    for (int fm = 0; fm < 2; ++fm)
#pragma unroll
        for (int fn = 0; fn < 4; ++fn)
#pragma unroll
            for (int r = 0; r < 4; ++r) {
                float e = __expf(acc[fm][fn][r] - jmax[fn]);
                acc[fm][fn][r] = e;
                ps[fn] += e;
            }
#pragma unroll
    for (int fn = 0; fn < 4; ++fn) {
        ps[fn] += __shfl_xor(ps[fn], 16, 64);
        ps[fn] += __shfl_xor(ps[fn], 32, 64);
    }
    if (l < 16) {
#pragma unroll
        for (int fn = 0; fn < 4; ++fn) wredB[w][fn * 16 + l] = ps[fn];
    }
    __syncthreads();

    float rinv[4];
#pragma unroll
    for (int fn = 0; fn < 4; ++fn) {
        float s = 0.f;
#pragma unroll
        for (int ww = 0; ww < 16; ++ww) s += wredB[ww][fn * 16 + l15];
        rinv[fn] = 1.f / s;
    }

    // ---- out[b,oo,i] = sp_v[oo] * sum_j coef[oo,j]   (FP32 store)
#pragma unroll
    for (int fm = 0; fm < 2; ++fm) {
#pragma unroll
        for (int r = 0; r < 4; ++r) {
            float tsum = 0.f;
#pragma unroll
            for (int fn = 0; fn < 4; ++fn) tsum += acc[fm][fn][r] * rinv[fn];
            tsum += __shfl_xor(tsum, 1, 64);
            tsum += __shfl_xor(tsum, 2, 64);
            tsum += __shfl_xor(tsum, 4, 64);
            tsum += __shfl_xor(tsum, 8, 64);
            if (l15 == 0) {
                int oo = w * 32 + fm * 16 + lk * 4 + r;
                out[((size_t)b * 512 + oo) * 32 + ii] = vrow[oo] * tsum;
            }
        }
    }
}

// ---------------------------------------------------------------------------
extern "C" void kernel_launch(void* const* d_in, const int* in_sizes, int n_in,
                              void* d_out, int out_size, void* d_ws, size_t ws_size,
                              hipStream_t stream) {
    const float* sparse = (const float*)d_in[0];
    const float* dense  = (const float*)d_in[1];
    const float* Wq = (const float*)d_in[2];
    const float* sq = (const float*)d_in[3];
    const float* bq = (const float*)d_in[4];
    const float* Wk = (const float*)d_in[5];
    const float* sk = (const float*)d_in[6];
    const float* bk = (const float*)d_in[7];
    const float* Wv = (const float*)d_in[8];
    const float* sv = (const float*)d_in[9];
    const float* bv = (const float*)d_in[10];
    const float* Wg = (const float*)d_in[11];
    const float* sg = (const float*)d_in[12];
    const float* bg = (const float*)d_in[13];
    float* out = (float*)d_out;

    // workspace: [sp_q f32 2MB][sp_v f32 2MB][Wk f16 512KB][Wg f16 512KB]
    float* wsq = (float*)d_ws;
    float* wsv = wsq + 1024 * 512;
    _Float16* wkf = (_Float16*)(wsv + 1024 * 512);
    _Float16* wgf = wkf + 512 * 512;

    cvt_weights<<<512, 256, 0, stream>>>(Wk, Wg, wkf, wgf);
    qv_gemm<<<dim3(16, 8, 2), 256, 0, stream>>>(sparse, Wq, sq, bq, Wv, sv, bv, wsq, wsv);
    fused_attn<<<1024, 1024, 0, stream>>>(dense, wkf, wgf, wsq, wsv, sk, bk, sg, bg, out);
}

// Round 15
// 151.419 us; speedup vs baseline: 2.1887x; 1.0280x over previous
//
#include <hip/hip_runtime.h>
#include <hip/hip_bf16.h>

#define EMB 512
#define NSTK 32
#define NPNT 64
#define BSZ 32

typedef __attribute__((ext_vector_type(8))) _Float16 f16x8;
typedef __attribute__((ext_vector_type(4))) float f32x4;
typedef __attribute__((ext_vector_type(4))) unsigned short us4;
typedef __attribute__((ext_vector_type(8))) unsigned short us8;

static __device__ __forceinline__ unsigned short f16bits(float x) {
    _Float16 h = (_Float16)x;
    return *reinterpret_cast<unsigned short*>(&h);
}

// async global->LDS DMA: dest = wave-uniform lds base + lane*16 (m104 semantics)
#define GLL(gsrc, ldst)                                                         \
    __builtin_amdgcn_global_load_lds(                                           \
        (const __attribute__((address_space(1))) void*)(gsrc),                  \
        (__attribute__((address_space(3))) void*)(ldst), 16, 0, 0)

#define SBAR() __builtin_amdgcn_s_barrier()

// ---------------------------------------------------------------------------
// Kernel AB (merged): blocks [0,512) convert Wk/Wg -> f16; blocks [512,768)
// run the fp32 qv GEMM. One launch instead of two.
// ---------------------------------------------------------------------------
__global__ __launch_bounds__(256)
void prep(const float* __restrict__ wk, const float* __restrict__ wg,
          _Float16* __restrict__ wkf, _Float16* __restrict__ wgf,
          const float* __restrict__ sparse,
          const float* __restrict__ Wq, const float* __restrict__ sq, const float* __restrict__ bq,
          const float* __restrict__ Wv, const float* __restrict__ sv, const float* __restrict__ bv,
          float* __restrict__ outq, float* __restrict__ outv) {
    if (blockIdx.x < 512) {
        int idx = blockIdx.x * blockDim.x + threadIdx.x;   // 0..131071
        const float* src;
        _Float16* dst;
        int k;
        if (idx < 65536) { src = wk; dst = wkf; k = idx; }
        else             { src = wg; dst = wgf; k = idx - 65536; }
        f32x4 v = *reinterpret_cast<const f32x4*>(src + (size_t)k * 4);
        us4 o;
#pragma unroll
        for (int e = 0; e < 4; ++e) o[e] = f16bits(v[e]);
        *reinterpret_cast<us4*>(dst + (size_t)k * 4) = o;
        return;
    }

    const int bid = blockIdx.x - 512;            // 0..255
    const int bx = bid & 15, by = (bid >> 4) & 7, bz = bid >> 7;
    const float* W  = (bz == 0) ? Wq : Wv;
    const float* sc = (bz == 0) ? sq : sv;
    const float* bi = (bz == 0) ? bq : bv;
    float* orow     = (bz == 0) ? outq : outv;

    __shared__ float Wt[64][33];
    __shared__ float St[32][65];

    const int m0 = bx * 64;
    const int o0 = by * 64;
    const int t  = threadIdx.x;
    const int ty = t >> 4, tx = t & 15;

    float acc[4][4] = {};

    for (int k0 = 0; k0 < 512; k0 += 32) {
        {
            int ol = t >> 2, kl = (t & 3) * 8;
            const float* p = W + (size_t)(o0 + ol) * 512 + k0 + kl;
            f32x4 v0 = *reinterpret_cast<const f32x4*>(p);
            f32x4 v1 = *reinterpret_cast<const f32x4*>(p + 4);
#pragma unroll
            for (int e = 0; e < 4; ++e) { Wt[ol][kl + e] = v0[e]; Wt[ol][kl + 4 + e] = v1[e]; }
        }
        {
            int kl = t >> 3, ml = (t & 7) * 8;
            int mm = m0 + ml;
            int bb = mm >> 5, iidx = mm & 31;
            const float* p = sparse + (size_t)bb * 16384 + (size_t)(k0 + kl) * 32 + iidx;
            f32x4 v0 = *reinterpret_cast<const f32x4*>(p);
            f32x4 v1 = *reinterpret_cast<const f32x4*>(p + 4);
#pragma unroll
            for (int e = 0; e < 4; ++e) { St[kl][ml + e] = v0[e]; St[kl][ml + 4 + e] = v1[e]; }
        }
        __syncthreads();
#pragma unroll
        for (int kk = 0; kk < 32; ++kk) {
            float av[4], bvv[4];
#pragma unroll
            for (int e = 0; e < 4; ++e) av[e]  = Wt[ty * 4 + e][kk];
#pragma unroll
            for (int e = 0; e < 4; ++e) bvv[e] = St[kk][tx * 4 + e];
#pragma unroll
            for (int a = 0; a < 4; ++a)
#pragma unroll
                for (int bb2 = 0; bb2 < 4; ++bb2) acc[a][bb2] += av[a] * bvv[bb2];
        }
        __syncthreads();
    }
#pragma unroll
    for (int ae = 0; ae < 4; ++ae) {
        int o = o0 + ty * 4 + ae;
        float s = sc[o], bb2 = bi[o];
#pragma unroll
        for (int be = 0; be < 4; ++be) {
            int mm = m0 + tx * 4 + be;
            float h = acc[ae][be] * s + bb2;
            h = (h >= 0.f) ? h : 0.2f * h;
            orow[(size_t)mm * 512 + o] = h;
        }
    }
}

// ---------------------------------------------------------------------------
// Kernel C: fused main. One WG (16 waves, 1024 thr) per (b,i).
// Barrier-free K-loops (WP rows wave-private, readiness via vmcnt(2)).
// R15: + race-fix barrier between GEMM1 and epilogue1 (R14 had fast waves
// overwriting XH while slow waves still read it); + B-frag reads hoisted
// above the vmcnt wait; + setprio around the MFMA cluster (T5).
// ---------------------------------------------------------------------------
__global__ __launch_bounds__(1024, 4)
void fused_attn(const float* __restrict__ dense,
                const _Float16* __restrict__ wkf,
                const _Float16* __restrict__ wgf,
                const float* __restrict__ wsq,
                const float* __restrict__ wsv,
                const float* __restrict__ sk, const float* __restrict__ bk,
                const float* __restrict__ sg, const float* __restrict__ bg,
                float* __restrict__ out) {
    __shared__ __align__(16) _Float16 XH[64][520];     // 66.5 KB, X -> D (f16)
    __shared__ __align__(16) _Float16 WP[2][512 * 32]; // 2 x 32 KB weight panels
    __shared__ __align__(16) float qrow[512];
    __shared__ __align__(16) float vrow[512];
    __shared__ float wredA[16][64];
    __shared__ float wredB[16][64];

    const int m   = blockIdx.x;        // 0..1023
    const int b   = m >> 5, ii = m & 31;
    const int tid = threadIdx.x;       // 0..1023
    const int w   = tid >> 6;          // wave 0..15
    const int l   = tid & 63;
    const int l15 = l & 15;
    const int lk  = l >> 4;            // 0..3

    // swizzled k-chunk this lane DMAs (m173 pre-swizzled source)
    const int tsw = ((l & 3) - ((l >> 3) & 3)) & 3;
    const int orl = l >> 2;

    // ---- prologue: DMA Wk panel 0 into WP[0] (overlaps X staging)
    {
#pragma unroll
        for (int ih = 0; ih < 2; ++ih) {
            const int o = w * 32 + ih * 16 + orl;
            GLL(wkf + (size_t)o * 512 + tsw * 8,
                &WP[0][(w * 32 + ih * 16) * 32]);
        }
    }

    if (tid < 512) qrow[tid] = wsq[(size_t)m * 512 + tid];
    else           vrow[tid - 512] = wsv[(size_t)m * 512 + (tid - 512)];

    {   // stage X (f16): thread owns j-row l, c-block [w*32, +32)
        const float* src = dense + (size_t)b * 512 * 2048 + (size_t)ii * 64 + l;
#pragma unroll
        for (int e8 = 0; e8 < 4; ++e8) {
            const int c0 = w * 32 + e8 * 8;
            us8 pk;
#pragma unroll
            for (int e = 0; e < 8; ++e)
                pk[e] = f16bits(src[(size_t)(c0 + e) * 2048]);
            *reinterpret_cast<us8*>(&XH[l][c0]) = pk;
        }
    }
    __syncthreads();   // full drain once: X staged + panel 0 resident

    f32x4 acc[2][4];
#pragma unroll
    for (int fm = 0; fm < 2; ++fm)
#pragma unroll
        for (int fn = 0; fn < 4; ++fn) acc[fm][fn] = (f32x4){0.f, 0.f, 0.f, 0.f};

    const int aslot = (lk + ((l15 >> 1) & 3)) & 3;

    // ---- GEMM1: dn_k[o,j] = sum_c Wk[o,c] * X[c,j]   (barrier-free K-loop)
    for (int ks = 0; ks < 16; ++ks) {
        {   // issue next panel (last iter issues Wg panel 0)
            const _Float16* wsp = (ks < 15) ? (wkf + (size_t)(ks + 1) * 32) : wgf;
            _Float16* pb = WP[(ks + 1) & 1];
#pragma unroll
            for (int ih = 0; ih < 2; ++ih) {
                const int o = w * 32 + ih * 16 + orl;
                GLL(wsp + (size_t)o * 512 + tsw * 8,
                    pb + (w * 32 + ih * 16) * 32);
            }
        }
        // B-frags don't depend on the panel: load them before the wait
        f16x8 bf[4];
#pragma unroll
        for (int fn = 0; fn < 4; ++fn)
            bf[fn] = *reinterpret_cast<const f16x8*>(&XH[fn * 16 + l15][ks * 32 + lk * 8]);
        asm volatile("s_waitcnt vmcnt(2)" ::: "memory");   // own panel ks landed
        {
            const _Float16* pbuf = WP[ks & 1];
            f16x8 af[2];
#pragma unroll
            for (int fm = 0; fm < 2; ++fm)
                af[fm] = *reinterpret_cast<const f16x8*>(
                    pbuf + (w * 32 + fm * 16 + l15) * 32 + aslot * 8);
            __builtin_amdgcn_s_setprio(1);
#pragma unroll
            for (int fm = 0; fm < 2; ++fm)
#pragma unroll
                for (int fn = 0; fn < 4; ++fn)
                    acc[fm][fn] = __builtin_amdgcn_mfma_f32_16x16x32_f16(af[fm], bf[fn], acc[fm][fn], 0, 0, 0);
            __builtin_amdgcn_s_setprio(0);
        }
        // no barrier: WP rows are wave-private; XH is read-only here
    }

    // RACE FIX (R14 bug): all waves must finish reading XH (X) before any
    // wave's epilogue1 overwrites it with D. Reads are consumed by MFMAs
    // above, so arrival-sync suffices; lgkmcnt(0) for belt-and-braces.
    asm volatile("s_waitcnt lgkmcnt(0)" ::: "memory");
    SBAR();

    // ---- epilogue1: d = q - lrelu(acc*sk+bk), f16, write D over XH
#pragma unroll
    for (int fm = 0; fm < 2; ++fm) {
        const int o0 = w * 32 + fm * 16 + lk * 4;
        f32x4 skv = *reinterpret_cast<const f32x4*>(sk + o0);
        f32x4 bkv = *reinterpret_cast<const f32x4*>(bk + o0);
        f32x4 qv4 = *reinterpret_cast<const f32x4*>(&qrow[o0]);
#pragma unroll
        for (int fn = 0; fn < 4; ++fn) {
            const int j = fn * 16 + l15;
            us4 pkh;
#pragma unroll
            for (int r = 0; r < 4; ++r) {
                float h = acc[fm][fn][r] * skv[r] + bkv[r];
                h = (h >= 0.f) ? h : 0.2f * h;
                pkh[r] = f16bits(qv4[r] - h);
            }
            *reinterpret_cast<us4*>(&XH[j][o0]) = pkh;   // 8B store, o0 % 4 == 0
        }
    }
    asm volatile("s_waitcnt lgkmcnt(0)" ::: "memory");
    SBAR();   // D visible to all waves (Wg panel-0 DMA still in flight - OK)

    // ---- GEMM2: g[oo,j] = sum_o Wg[oo,o] * d[o,j]   (barrier-free K-loop)
#pragma unroll
    for (int fm = 0; fm < 2; ++fm)
#pragma unroll
        for (int fn = 0; fn < 4; ++fn) acc[fm][fn] = (f32x4){0.f, 0.f, 0.f, 0.f};

    for (int ks = 0; ks < 16; ++ks) {
        if (ks < 15) {   // issue next Wg panel
            const _Float16* wsp = wgf + (size_t)(ks + 1) * 32;
            _Float16* pb = WP[(ks + 1) & 1];
#pragma unroll
            for (int ih = 0; ih < 2; ++ih) {
                const int o = w * 32 + ih * 16 + orl;
                GLL(wsp + (size_t)o * 512 + tsw * 8,
                    pb + (w * 32 + ih * 16) * 32);
            }
        }
        f16x8 bf[4];
#pragma unroll
        for (int fn = 0; fn < 4; ++fn)
            bf[fn] = *reinterpret_cast<const f16x8*>(&XH[fn * 16 + l15][ks * 32 + lk * 8]);
        if (ks < 15) asm volatile("s_waitcnt vmcnt(2)" ::: "memory");
        else         asm volatile("s_waitcnt vmcnt(0)" ::: "memory");
        {
            const _Float16* pbuf = WP[ks & 1];
            f16x8 af[2];
#pragma unroll
            for (int fm = 0; fm < 2; ++fm)
                af[fm] = *reinterpret_cast<const f16x8*>(
                    pbuf + (w * 32 + fm * 16 + l15) * 32 + aslot * 8);
            __builtin_amdgcn_s_setprio(1);
#pragma unroll
            for (int fm = 0; fm < 2; ++fm)
#pragma unroll
                for (int fn = 0; fn < 4; ++fn)
                    acc[fm][fn] = __builtin_amdgcn_mfma_f32_16x16x32_f16(af[fm], bf[fn], acc[fm][fn], 0, 0, 0);
            __builtin_amdgcn_s_setprio(0);
        }
        // no barrier: WP rows wave-private, XH read-only (no writer until softmax bufs)
    }

    // ---- epilogue2 in place: g = lrelu(acc*sg+bg)
#pragma unroll
    for (int fm = 0; fm < 2; ++fm) {
        const int o0 = w * 32 + fm * 16 + lk * 4;
        f32x4 sgv = *reinterpret_cast<const f32x4*>(sg + o0);
        f32x4 bgv = *reinterpret_cast<const f32x4*>(bg + o0);
#pragma unroll
        for (int fn = 0; fn < 4; ++fn)
#pragma unroll
            for (int r = 0; r < 4; ++r) {
                float h = acc[fm][fn][r] * sgv[r] + bgv[r];
                acc[fm][fn][r] = (h >= 0.f) ? h : 0.2f * h;
            }
    }

    // ---- softmax over the 512 channels, per j column
    float pm[4];
#pragma unroll
    for (int fn = 0; fn < 4; ++fn) {
        float mx = -1e30f;
#pragma unroll
        for (int fm = 0; fm < 2; ++fm)
#pragma unroll
            for (int r = 0; r < 4; ++r) mx = fmaxf(mx, acc[fm][fn][r]);
        mx = fmaxf(mx, __shfl_xor(mx, 16, 64));
        mx = fmaxf(mx, __shfl_xor(mx, 32, 64));
        pm[fn] = mx;
    }
    if (l < 16) {
#pragma unroll
        for (int fn = 0; fn < 4; ++fn) wredA[w][fn * 16 + l] = pm[fn];
    }
    __syncthreads();

    float jmax[4];
#pragma unroll
    for (int fn = 0; fn < 4; ++fn) {
        float mx = wredA[0][fn * 16 + l15];
#pragma unroll
        for (int ww = 1; ww < 16; ++ww) mx = fmaxf(mx, wredA[ww][fn * 16 + l15]);
        jmax[fn] = mx;
    }

    float ps[4] = {0.f, 0.f, 0.f, 0.f};
#pragma unroll
    for (int fm = 0; fm < 2; ++fm)
#pragma unroll
        for (int fn = 0; fn < 4; ++fn)
#pragma unroll
            for (int r = 0; r < 4; ++r) {
                float e = __expf(acc[fm][fn][r] - jmax[fn]);
                acc[fm][fn][r] = e;
                ps[fn] += e;
            }
#pragma unroll
    for (int fn = 0; fn < 4; ++fn) {
        ps[fn] += __shfl_xor(ps[fn], 16, 64);
        ps[fn] += __shfl_xor(ps[fn], 32, 64);
    }
    if (l < 16) {
#pragma unroll
        for (int fn = 0; fn < 4; ++fn) wredB[w][fn * 16 + l] = ps[fn];
    }
    __syncthreads();

    float rinv[4];
#pragma unroll
    for (int fn = 0; fn < 4; ++fn) {
        float s = 0.f;
#pragma unroll
        for (int ww = 0; ww < 16; ++ww) s += wredB[ww][fn * 16 + l15];
        rinv[fn] = 1.f / s;
    }

    // ---- out[b,oo,i] = sp_v[oo] * sum_j coef[oo,j]   (FP32 store)
#pragma unroll
    for (int fm = 0; fm < 2; ++fm) {
#pragma unroll
        for (int r = 0; r < 4; ++r) {
            float tsum = 0.f;
#pragma unroll
            for (int fn = 0; fn < 4; ++fn) tsum += acc[fm][fn][r] * rinv[fn];
            tsum += __shfl_xor(tsum, 1, 64);
            tsum += __shfl_xor(tsum, 2, 64);
            tsum += __shfl_xor(tsum, 4, 64);
            tsum += __shfl_xor(tsum, 8, 64);
            if (l15 == 0) {
                int oo = w * 32 + fm * 16 + lk * 4 + r;
                out[((size_t)b * 512 + oo) * 32 + ii] = vrow[oo] * tsum;
            }
        }
    }
}

// ---------------------------------------------------------------------------
extern "C" void kernel_launch(void* const* d_in, const int* in_sizes, int n_in,
                              void* d_out, int out_size, void* d_ws, size_t ws_size,
                              hipStream_t stream) {
    const float* sparse = (const float*)d_in[0];
    const float* dense  = (const float*)d_in[1];
    const float* Wq = (const float*)d_in[2];
    const float* sq = (const float*)d_in[3];
    const float* bq = (const float*)d_in[4];
    const float* Wk = (const float*)d_in[5];
    const float* sk = (const float*)d_in[6];
    const float* bk = (const float*)d_in[7];
    const float* Wv = (const float*)d_in[8];
    const float* sv = (const float*)d_in[9];
    const float* bv = (const float*)d_in[10];
    const float* Wg = (const float*)d_in[11];
    const float* sg = (const float*)d_in[12];
    const float* bg = (const float*)d_in[13];
    float* out = (float*)d_out;

    // workspace: [sp_q f32 2MB][sp_v f32 2MB][Wk f16 512KB][Wg f16 512KB]
    float* wsq = (float*)d_ws;
    float* wsv = wsq + 1024 * 512;
    _Float16* wkf = (_Float16*)(wsv + 1024 * 512);
    _Float16* wgf = wkf + 512 * 512;

    prep<<<768, 256, 0, stream>>>(Wk, Wg, wkf, wgf,
                                  sparse, Wq, sq, bq, Wv, sv, bv, wsq, wsv);
    fused_attn<<<1024, 1024, 0, stream>>>(dense, wkf, wgf, wsq, wsv, sk, bk, sg, bg, out);
}